// Round 7
// baseline (104.521 us; speedup 1.0000x reference)
//
#include <hip/hip_runtime.h>
#include <math.h>

#define NB 1024   // batch
#define NC 64     // input dim
#define NH 128    // hidden dim
#define MAX_IT 200   // R21: duration-neutral vs 500 (worst block converges <200)
#define TOLF 6e-3f   // ||r|| < TOL certifies ||x-x*|| < TOL (1-strong mono).

typedef _Float16 f16x8 __attribute__((ext_vector_type(8)));
typedef float    f32x4 __attribute__((ext_vector_type(4)));
typedef _Float16 h2    __attribute__((ext_vector_type(2)));

#define MFMA(a, b, c) __builtin_amdgcn_mfma_f32_16x16x32_f16((a), (b), (c), 0, 0, 0)

__device__ __forceinline__ unsigned pack_h2(float a, float b) {
    union { h2 h; unsigned u; } cv;
    cv.h.x = (_Float16)a; cv.h.y = (_Float16)b; return cv.u;
}
__device__ __forceinline__ float rcp_fast(float x) {
#if __has_builtin(__builtin_amdgcn_rcpf)
    return __builtin_amdgcn_rcpf(x);
#else
    return 1.0f / x;
#endif
}
// sigmoid + softplus sharing one exp
__device__ __forceinline__ void sigsp(float a, float& sig, float& sp) {
    const float e = __expf(-fabsf(a));
    const float r = rcp_fast(1.0f + e);
    sig = (a >= 0.0f) ? r : e * r;
    sp  = fmaxf(a, 0.0f) + __logf(1.0f + e);
}
__device__ __forceinline__ float sigm(float a) {
    const float e = __expf(-fabsf(a));
    const float r = rcp_fast(1.0f + e);
    return (a >= 0.0f) ? r : e * r;
}
__device__ __forceinline__ float clp(float x) { return fmaxf(x, 0.0f); }

// fragment loaders: 8 fp32 -> f16x8, same element order as the old LDS staging
__device__ __forceinline__ f16x8 ld8(const float* p) {
    const float4 a = ((const float4*)p)[0];
    const float4 b = ((const float4*)p)[1];
    f16x8 r;
    r[0]=(_Float16)a.x; r[1]=(_Float16)a.y; r[2]=(_Float16)a.z; r[3]=(_Float16)a.w;
    r[4]=(_Float16)b.x; r[5]=(_Float16)b.y; r[6]=(_Float16)b.z; r[7]=(_Float16)b.w;
    return r;
}
__device__ __forceinline__ f16x8 ld8_clip(const float* p) {
    const float4 a = ((const float4*)p)[0];
    const float4 b = ((const float4*)p)[1];
    f16x8 r;
    r[0]=(_Float16)clp(a.x); r[1]=(_Float16)clp(a.y); r[2]=(_Float16)clp(a.z); r[3]=(_Float16)clp(a.w);
    r[4]=(_Float16)clp(b.x); r[5]=(_Float16)clp(b.y); r[6]=(_Float16)clp(b.z); r[7]=(_Float16)clp(b.w);
    return r;
}
__device__ __forceinline__ f16x8 ld8_str(const float* p, int stride) {
    f16x8 r;
    #pragma unroll
    for (int j = 0; j < 8; ++j) r[j] = (_Float16)p[j * stride];
    return r;
}
__device__ __forceinline__ f16x8 ld8_str_clip(const float* p, int stride) {
    f16x8 r;
    #pragma unroll
    for (int j = 0; j < 8; ++j) r[j] = (_Float16)clp(p[j * stride]);
    return r;
}

// R23 = R21 math/solver EXACTLY (adaptive Richardson, 5 barriers, weights in
// registers — R22's fixed-step 4-barrier variant regressed 83->103 us: the
// adaptive lam is load-bearing: it stays 1.0 on benign samples and halves
// below 0.22 on stiff ones; fixed 0.22 oscillated on stiff samples to the
// MAX_IT cap). Change: block re-partition 512thr/4smp/256blk (1 block/CU)
// -> 256thr/2smp/512blk (2 blocks/CU). At 1 block/CU every __syncthreads
// stalls ALL resident waves (lockstep dead time x5/iter); with 2 independent
// blocks/CU, block A's barrier drains overlap block B's compute. Per-CU
// compute unchanged (4 samples/CU); per-wave forward work doubles (2 m-tiles
// per wave); col phase loses its (redundant) pair duplication.
// VGPR: 32 weight frags (128) + 6 bias float4 (24) + state ~ 210 < 256 =>
// __launch_bounds__(256,2) holds 2 waves/SIMD with no spill.
__launch_bounds__(256, 2)
__global__ void blnn_kernel(const float* __restrict__ xin,
                            const float* __restrict__ Wy0,
                            const float* __restrict__ by0,
                            const float* __restrict__ Wy1,
                            const float* __restrict__ by1,
                            const float* __restrict__ Wz1,
                            const float* __restrict__ Wy2,
                            const float* __restrict__ by2,
                            const float* __restrict__ Wz2,
                            float* __restrict__ out)
{
    __shared__ __align__(16) _Float16 xact [2 * 80];   // x  per sample (pad 64->80)
    __shared__ __align__(16) _Float16 h0act[2 * 144];  // h0 per sample (pad 128->144)
    __shared__ __align__(16) _Float16 v1act[2 * 144];  // ~v1 (no sg2)
    __shared__ __align__(16) _Float16 v0act[2 * 144];
    __shared__ __align__(16) float hp[16];    // head partials [n4][mt0..7]
    __shared__ __align__(16) float pxp[8];    // wy2.x partials [n4][cm]
    __shared__ __align__(16) float npar[8];   // norm^2 partials [n4][cm]

    const int tid  = threadIdx.x;
    const int w    = tid >> 6;        // 0..3  (wave; also col m-tile cm = w)
    const int l    = tid & 63;
    const int n    = l & 15;          // MFMA col
    const int n4   = n & 1;           // real sample (2 per block)
    const int quad = l >> 4;
    const int blk2 = blockIdx.x * 2;

    // ---- weights into REGISTERS (one-time; same per-lane frag layout) ----
    const int rA0 = w * 32 + n;        // forward m-tile 2w   row
    const int rA1 = w * 32 + 16 + n;   // forward m-tile 2w+1 row
    const int rT  = w * 16 + n;        // transposed row (c index), cm = w
    const int kq  = quad * 8;

    f16x8 wa0[2][2], wa1[2][2];        // [m-tile i][k-slice]
    #pragma unroll
    for (int ks = 0; ks < 2; ++ks) {
        wa0[0][ks] = ld8(Wy0 + rA0 * 64 + ks * 32 + kq);
        wa0[1][ks] = ld8(Wy0 + rA1 * 64 + ks * 32 + kq);
        wa1[0][ks] = ld8(Wy1 + rA0 * 64 + ks * 32 + kq);
        wa1[1][ks] = ld8(Wy1 + rA1 * 64 + ks * 32 + kq);
    }
    f16x8 waz[2][4], wzt[2][4], w1t[4], w0t[4];
    #pragma unroll
    for (int ks = 0; ks < 4; ++ks) {
        waz[0][ks] = ld8_clip(Wz1 + rA0 * 128 + ks * 32 + kq);             // Wz1+ row-major
        waz[1][ks] = ld8_clip(Wz1 + rA1 * 128 + ks * 32 + kq);
        wzt[0][ks] = ld8_str_clip(Wz1 + (ks * 32 + kq) * 128 + rA0, 128);  // Wz1+^T
        wzt[1][ks] = ld8_str_clip(Wz1 + (ks * 32 + kq) * 128 + rA1, 128);
        w1t[ks]    = ld8_str(Wy1 + (ks * 32 + kq) * 64 + rT, 64);          // Wy1^T
        w0t[ks]    = ld8_str(Wy0 + (ks * 32 + kq) * 64 + rT, 64);          // Wy0^T
    }
    float4 bb0[2], bb1[2], wzq[2];
    #pragma unroll
    for (int i = 0; i < 2; ++i) {
        bb0[i] = *(const float4*)(by0 + (w * 2 + i) * 16 + quad * 4);
        bb1[i] = *(const float4*)(by1 + (w * 2 + i) * 16 + quad * 4);
        const float4 t = *(const float4*)(Wz2 + (w * 2 + i) * 16 + quad * 4);
        wzq[i].x = clp(t.x); wzq[i].y = clp(t.y); wzq[i].z = clp(t.z); wzq[i].w = clp(t.w);
    }

    if (tid < 128) {   // x0 = z into act layout (2 samples x 64)
        const int nn = tid >> 6, cc = tid & 63;
        xact[nn * 80 + cc] = (_Float16)xin[(blk2 + nn) * 64 + cc];
    }

    // ---- col-role state: rows c = w*16 + quad*4 + r, sample n4 ----
    const float4 z4  = ((const float4*)xin)[(blk2 + n4) * 16 + w * 4 + quad];
    const float4 wy4 = ((const float4*)Wy2)[w * 4 + quad];
    float zr[4]   = {z4.x, z4.y, z4.z, z4.w};
    float wy2r[4] = {wy4.x, wy4.y, wy4.z, wy4.w};
    float xcur[4] = {zr[0], zr[1], zr[2], zr[3]};
    float lamE = 1.0f, prevn2 = 3.4e38f;
    const float b2 = by2[0];

    {   // px = sum_c wy2[c]*x[c] for first iteration
        float pxs = wy2r[0]*xcur[0] + wy2r[1]*xcur[1] + wy2r[2]*xcur[2] + wy2r[3]*xcur[3];
        pxs += __shfl_xor(pxs, 16, 64);
        pxs += __shfl_xor(pxs, 32, 64);
        if (l < 2) pxp[l * 4 + w] = pxs;   // pxp[n4][cm]
    }
    __syncthreads();

    const _Float16* xrow  = xact  + n4 * 80;
    const _Float16* h0row = h0act + n4 * 144;
    const _Float16* v1row = v1act + n4 * 144;
    const _Float16* v0row = v0act + n4 * 144;

    float sig0[2][4];
    const float T2 = TOLF * TOLF;

    for (int it = 0; it < MAX_IT; ++it) {
        // ---- P1: preact0 = Wy0 x + by0 -> h0, sig0 (m-tiles 2w, 2w+1) ----
        f16x8 bx0 = *(const f16x8*)(xrow + quad * 8);
        f16x8 bx1 = *(const f16x8*)(xrow + 32 + quad * 8);
        #pragma unroll
        for (int i = 0; i < 2; ++i) {
            f32x4 acc = {0.f, 0.f, 0.f, 0.f};
            acc = MFMA(wa0[i][0], bx0, acc);
            acc = MFMA(wa0[i][1], bx1, acc);
            float sp0, sp1, sp2, sp3;
            sigsp(acc[0] + bb0[i].x, sig0[i][0], sp0);
            sigsp(acc[1] + bb0[i].y, sig0[i][1], sp1);
            sigsp(acc[2] + bb0[i].z, sig0[i][2], sp2);
            sigsp(acc[3] + bb0[i].w, sig0[i][3], sp3);
            if (n < 2)
                *(uint2*)&h0act[n4 * 144 + (w * 2 + i) * 16 + quad * 4] =
                    make_uint2(pack_h2(sp0, sp1), pack_h2(sp2, sp3));
        }
        __syncthreads();   // B1: h0 ready

        // ---- P2: preact1 -> sig1,h1 ; head partials ; ~v1 (m-tiles 2w,2w+1) ----
        f16x8 bh0 = *(const f16x8*)(h0row + quad * 8);
        f16x8 bh1 = *(const f16x8*)(h0row + 32 + quad * 8);
        f16x8 bh2 = *(const f16x8*)(h0row + 64 + quad * 8);
        f16x8 bh3 = *(const f16x8*)(h0row + 96 + quad * 8);
        float hsum[2];
        #pragma unroll
        for (int i = 0; i < 2; ++i) {
            f32x4 acc = {0.f, 0.f, 0.f, 0.f};
            acc = MFMA(waz[i][0], bh0, acc);
            acc = MFMA(waz[i][1], bh1, acc);
            acc = MFMA(waz[i][2], bh2, acc);
            acc = MFMA(waz[i][3], bh3, acc);
            acc = MFMA(wa1[i][0], bx0, acc);
            acc = MFMA(wa1[i][1], bx1, acc);
            float s1, h1, hs = 0.0f;
            sigsp(acc[0] + bb1[i].x, s1, h1); hs = fmaf(wzq[i].x, h1, hs);
            const float t0 = s1 * wzq[i].x;
            sigsp(acc[1] + bb1[i].y, s1, h1); hs = fmaf(wzq[i].y, h1, hs);
            const float t1 = s1 * wzq[i].y;
            sigsp(acc[2] + bb1[i].z, s1, h1); hs = fmaf(wzq[i].z, h1, hs);
            const float t2 = s1 * wzq[i].z;
            sigsp(acc[3] + bb1[i].w, s1, h1); hs = fmaf(wzq[i].w, h1, hs);
            const float t3 = s1 * wzq[i].w;
            hsum[i] = hs;
            if (n < 2)
                *(uint2*)&v1act[n4 * 144 + (w * 2 + i) * 16 + quad * 4] =
                    make_uint2(pack_h2(t0, t1), pack_h2(t2, t3));
        }
        hsum[0] += __shfl_xor(hsum[0], 16, 64);
        hsum[0] += __shfl_xor(hsum[0], 32, 64);
        hsum[1] += __shfl_xor(hsum[1], 16, 64);
        hsum[1] += __shfl_xor(hsum[1], 32, 64);
        if (l < 2) {                       // hp[n4][mt]
            hp[l * 8 + w * 2 + 0] = hsum[0];
            hp[l * 8 + w * 2 + 1] = hsum[1];
        }
        __syncthreads();   // B2: hp AND ~v1 ready (sg2 deferred)

        // ---- P4: sg2; v0 = sig0*sg2*(Wz1+^T ~v1) (m-tiles); accg (cm=w) ----
        float sg2c;
        {
            const float4 h0v = ((const float4*)hp)[n4 * 2];
            const float4 h1v = ((const float4*)hp)[n4 * 2 + 1];
            const float4 pv  = ((const float4*)pxp)[n4];
            sg2c = sigm(h0v.x + h0v.y + h0v.z + h0v.w +
                        h1v.x + h1v.y + h1v.z + h1v.w +
                        pv.x + pv.y + pv.z + pv.w + b2);
        }
        f16x8 bv10 = *(const f16x8*)(v1row + quad * 8);
        f16x8 bv11 = *(const f16x8*)(v1row + 32 + quad * 8);
        f16x8 bv12 = *(const f16x8*)(v1row + 64 + quad * 8);
        f16x8 bv13 = *(const f16x8*)(v1row + 96 + quad * 8);
        #pragma unroll
        for (int i = 0; i < 2; ++i) {
            f32x4 acc = {0.f, 0.f, 0.f, 0.f};
            acc = MFMA(wzt[i][0], bv10, acc);
            acc = MFMA(wzt[i][1], bv11, acc);
            acc = MFMA(wzt[i][2], bv12, acc);
            acc = MFMA(wzt[i][3], bv13, acc);
            const float a0 = sig0[i][0] * sg2c * acc[0];
            const float a1 = sig0[i][1] * sg2c * acc[1];
            const float a2 = sig0[i][2] * sg2c * acc[2];
            const float a3 = sig0[i][3] * sg2c * acc[3];
            if (n < 2)
                *(uint2*)&v0act[n4 * 144 + (w * 2 + i) * 16 + quad * 4] =
                    make_uint2(pack_h2(a0, a1), pack_h2(a2, a3));
        }
        f32x4 accg = {0.f, 0.f, 0.f, 0.f};   // Wy1^T ~v1 (col m-tile w)
        accg = MFMA(w1t[0], bv10, accg);
        accg = MFMA(w1t[1], bv11, accg);
        accg = MFMA(w1t[2], bv12, accg);
        accg = MFMA(w1t[3], bv13, accg);
        __syncthreads();   // B3: v0 ready

        // ---- P6: g = x + sg2*wy2 + sg2*accg + Wy0^T v0 ; residual norm ----
        f16x8 bv00 = *(const f16x8*)(v0row + quad * 8);
        f16x8 bv01 = *(const f16x8*)(v0row + 32 + quad * 8);
        f16x8 bv02 = *(const f16x8*)(v0row + 64 + quad * 8);
        f16x8 bv03 = *(const f16x8*)(v0row + 96 + quad * 8);
        f32x4 acc0 = {0.f, 0.f, 0.f, 0.f};
        acc0 = MFMA(w0t[0], bv00, acc0);
        acc0 = MFMA(w0t[1], bv01, acc0);
        acc0 = MFMA(w0t[2], bv02, acc0);
        acc0 = MFMA(w0t[3], bv03, acc0);
        float resid[4];
        float r2 = 0.0f;
        #pragma unroll
        for (int r = 0; r < 4; ++r) {
            const float g = xcur[r] + sg2c * wy2r[r] + sg2c * accg[r] + acc0[r];
            resid[r] = zr[r] - g;
            r2 = fmaf(resid[r], resid[r], r2);
        }
        r2 += __shfl_xor(r2, 16, 64);
        r2 += __shfl_xor(r2, 32, 64);
        if (l < 2) npar[l * 4 + w] = r2;   // npar[n4][cm]
        __syncthreads();   // B4: norm partials ready

        const float4 q0 = ((const float4*)npar)[0];
        const float4 q1 = ((const float4*)npar)[1];
        const float s0 = q0.x + q0.y + q0.z + q0.w;
        const float s1 = q1.x + q1.y + q1.z + q1.w;
        if (s0 < T2 && s1 < T2) break;   // uniform

        const float myn2 = (n4 == 0) ? s0 : s1;
        if (myn2 >= T2) {                    // adaptive Richardson (R3 solver)
            if (myn2 > prevn2 * 0.998f) lamE *= 0.5f;
            const float step = fmaxf(lamE, 1.0f / (float)(it + 2));
            #pragma unroll
            for (int r = 0; r < 4; ++r) xcur[r] = fmaf(step, resid[r], xcur[r]);
            prevn2 = myn2;
        }
        {   // px partial for next iter + x writeback
            float pxs = wy2r[0]*xcur[0] + wy2r[1]*xcur[1] + wy2r[2]*xcur[2] + wy2r[3]*xcur[3];
            pxs += __shfl_xor(pxs, 16, 64);
            pxs += __shfl_xor(pxs, 32, 64);
            if (l < 2) pxp[l * 4 + w] = pxs;
        }
        if (n < 2)
            *(uint2*)&xact[n4 * 80 + w * 16 + quad * 4] =
                make_uint2(pack_h2(xcur[0], xcur[1]), pack_h2(xcur[2], xcur[3]));
        __syncthreads();   // B5: x ready
    }

    if (n < 2) {
        float4 o;
        o.x = xcur[0] + zr[0]; o.y = xcur[1] + zr[1];
        o.z = xcur[2] + zr[2]; o.w = xcur[3] + zr[3];
        ((float4*)out)[(blk2 + n4) * 16 + w * 4 + quad] = o;   // + CONVEX*z
    }
}

extern "C" void kernel_launch(void* const* d_in, const int* in_sizes, int n_in,
                              void* d_out, int out_size, void* d_ws, size_t ws_size,
                              hipStream_t stream) {
    const float* xin = (const float*)d_in[0];
    const float* Wy0 = (const float*)d_in[1];
    const float* by0 = (const float*)d_in[2];
    const float* Wy1 = (const float*)d_in[3];
    const float* by1 = (const float*)d_in[4];
    const float* Wz1 = (const float*)d_in[5];
    const float* Wy2 = (const float*)d_in[6];
    const float* by2 = (const float*)d_in[7];
    const float* Wz2 = (const float*)d_in[8];
    float* out = (float*)d_out;

    blnn_kernel<<<dim3(NB / 2), dim3(256), 0, stream>>>(
        xin, Wy0, by0, Wy1, by1, Wz1, Wy2, by2, Wz2, out);
}

// Round 8
// 84.042 us; speedup vs baseline: 1.2437x; 1.2437x over previous
//
#include <hip/hip_runtime.h>
#include <math.h>

#define NB 1024   // batch
#define NC 64     // input dim
#define NH 128    // hidden dim
#define MAX_IT 200   // R21: duration-neutral vs 500 (worst block converges <200)
#define TOLF 6e-3f   // ||r|| < TOL certifies ||x-x*|| < TOL (1-strong mono).

typedef _Float16 f16x8 __attribute__((ext_vector_type(8)));
typedef float    f32x4 __attribute__((ext_vector_type(4)));
typedef _Float16 h2    __attribute__((ext_vector_type(2)));

#define MFMA(a, b, c) __builtin_amdgcn_mfma_f32_16x16x32_f16((a), (b), (c), 0, 0, 0)

__device__ __forceinline__ unsigned pack_h2(float a, float b) {
    union { h2 h; unsigned u; } cv;
    cv.h.x = (_Float16)a; cv.h.y = (_Float16)b; return cv.u;
}
__device__ __forceinline__ float rcp_fast(float x) {
#if __has_builtin(__builtin_amdgcn_rcpf)
    return __builtin_amdgcn_rcpf(x);
#else
    return 1.0f / x;
#endif
}
// sigmoid + softplus sharing one exp
__device__ __forceinline__ void sigsp(float a, float& sig, float& sp) {
    const float e = __expf(-fabsf(a));
    const float r = rcp_fast(1.0f + e);
    sig = (a >= 0.0f) ? r : e * r;
    sp  = fmaxf(a, 0.0f) + __logf(1.0f + e);
}
__device__ __forceinline__ float sigm(float a) {
    const float e = __expf(-fabsf(a));
    const float r = rcp_fast(1.0f + e);
    return (a >= 0.0f) ? r : e * r;
}
__device__ __forceinline__ float clp(float x) { return fmaxf(x, 0.0f); }

// fragment loaders: 8 fp32 -> f16x8, same element order as the old LDS staging
__device__ __forceinline__ f16x8 ld8(const float* p) {
    const float4 a = ((const float4*)p)[0];
    const float4 b = ((const float4*)p)[1];
    f16x8 r;
    r[0]=(_Float16)a.x; r[1]=(_Float16)a.y; r[2]=(_Float16)a.z; r[3]=(_Float16)a.w;
    r[4]=(_Float16)b.x; r[5]=(_Float16)b.y; r[6]=(_Float16)b.z; r[7]=(_Float16)b.w;
    return r;
}
__device__ __forceinline__ f16x8 ld8_clip(const float* p) {
    const float4 a = ((const float4*)p)[0];
    const float4 b = ((const float4*)p)[1];
    f16x8 r;
    r[0]=(_Float16)clp(a.x); r[1]=(_Float16)clp(a.y); r[2]=(_Float16)clp(a.z); r[3]=(_Float16)clp(a.w);
    r[4]=(_Float16)clp(b.x); r[5]=(_Float16)clp(b.y); r[6]=(_Float16)clp(b.z); r[7]=(_Float16)clp(b.w);
    return r;
}
__device__ __forceinline__ f16x8 ld8_str(const float* p, int stride) {
    f16x8 r;
    #pragma unroll
    for (int j = 0; j < 8; ++j) r[j] = (_Float16)p[j * stride];
    return r;
}
__device__ __forceinline__ f16x8 ld8_str_clip(const float* p, int stride) {
    f16x8 r;
    #pragma unroll
    for (int j = 0; j < 8; ++j) r[j] = (_Float16)clp(p[j * stride]);
    return r;
}

// R24 = R18 structure EXACTLY (512 thr, 82.9 us, weights-in-regs: 20 frags =
// 80 VGPR, no spill) with the iteration cut 5 -> 4 barriers while KEEPING the
// adaptive Richardson solver (R3), adaptation delayed one iteration:
//   loop top (after prev iter's end-barrier): read npar -> break check;
//     halve lamE if ||r_{k-1}|| grew vs ||r_{k-2}||; freeze if < TOL.
//   P6: resid -> x += step*resid immediately (no global info needed) ->
//     write npar/pxp/xact -> ONE barrier.
// Attribution: R22 bundled {4-barrier, fixed step} and regressed because the
// FIXED step loses adaptivity (stiff samples oscillate to the cap; benign
// samples crawl). Deferred break itself was accuracy-safe in R22 (absmax
// 0.03125, passed). R23's counters (VGPR=128 cap -> spill, MfmaUtil 3%,
// VALUBusy 17%) confirm the loop is stall-dominated and the register budget
// must not grow => this change touches only barrier structure.
// Delayed halving = one extra bad step before a halve; R16 tolerated six
// lam=1.0 transient steps, so stability margin is ample.
__launch_bounds__(512, 1)
__global__ void blnn_kernel(const float* __restrict__ xin,
                            const float* __restrict__ Wy0,
                            const float* __restrict__ by0,
                            const float* __restrict__ Wy1,
                            const float* __restrict__ by1,
                            const float* __restrict__ Wz1,
                            const float* __restrict__ Wy2,
                            const float* __restrict__ by2,
                            const float* __restrict__ Wz2,
                            float* __restrict__ out)
{
    __shared__ __align__(16) _Float16 xact [4 * 80];   // x  per sample (pad 64->80)
    __shared__ __align__(16) _Float16 h0act[4 * 144];  // h0 per sample (pad 128->144)
    __shared__ __align__(16) _Float16 v1act[4 * 144];  // ~v1 (no sg2)
    __shared__ __align__(16) _Float16 v0act[4 * 144];
    __shared__ __align__(16) float hp[32];    // head partials [n4][w0..7]
    __shared__ __align__(16) float pxp[16];   // wy2.x partials [n4][cm]
    __shared__ __align__(16) float npar[16];  // norm^2 partials [n4][cm]

    const int tid  = threadIdx.x;
    const int w    = tid >> 6;        // 0..7
    const int cm   = w & 3;           // col-phase m-tile (pairs duplicate)
    const int l    = tid & 63;
    const int n    = l & 15;          // MFMA col
    const int n4   = n & 3;           // real sample
    const int quad = l >> 4;
    const int blk4 = blockIdx.x * 4;

    // ---- weights into REGISTERS (one-time; same frag order as R9 staging) ----
    const int rA = w * 16 + n;        // forward m-tile row, 0..127
    const int rT = cm * 16 + n;       // transposed row (c index), 0..63
    const int kq = quad * 8;

    f16x8 wa0[2], wa1[2];
    #pragma unroll
    for (int ks = 0; ks < 2; ++ks) {
        wa0[ks] = ld8(Wy0 + rA * 64 + ks * 32 + kq);
        wa1[ks] = ld8(Wy1 + rA * 64 + ks * 32 + kq);
    }
    f16x8 waz[4], wzt[4], w1t[4], w0t[4];
    #pragma unroll
    for (int ks = 0; ks < 4; ++ks) {
        waz[ks] = ld8_clip(Wz1 + rA * 128 + ks * 32 + kq);                 // Wz1+ row-major
        wzt[ks] = ld8_str_clip(Wz1 + (ks * 32 + kq) * 128 + rA, 128);      // Wz1+^T
        w1t[ks] = ld8_str(Wy1 + (ks * 32 + kq) * 64 + rT, 64);             // Wy1^T
        w0t[ks] = ld8_str(Wy0 + (ks * 32 + kq) * 64 + rT, 64);             // Wy0^T
    }
    const float4 bb0 = *(const float4*)(by0 + w * 16 + quad * 4);
    const float4 bb1 = *(const float4*)(by1 + w * 16 + quad * 4);
    float4 wzq;
    {
        const float4 t = *(const float4*)(Wz2 + w * 16 + quad * 4);
        wzq.x = clp(t.x); wzq.y = clp(t.y); wzq.z = clp(t.z); wzq.w = clp(t.w);
    }

    if (tid < 256) {   // x0 = z into act layout
        const int nn = tid >> 6, cc = tid & 63;
        xact[nn * 80 + cc] = (_Float16)xin[(blk4 + nn) * 64 + cc];
    }
    if (tid < 16) npar[tid] = 1e30f;   // it=0: no break, no halve, no freeze

    // ---- col-role state: rows c = cm*16 + quad*4 + r, sample n4 ----
    const float4 z4  = ((const float4*)xin)[(blk4 + n4) * 16 + cm * 4 + quad];
    const float4 wy4 = ((const float4*)Wy2)[cm * 4 + quad];
    float zr[4]   = {z4.x, z4.y, z4.z, z4.w};
    float wy2r[4] = {wy4.x, wy4.y, wy4.z, wy4.w};
    float xcur[4] = {zr[0], zr[1], zr[2], zr[3]};
    float lamE = 1.0f, prevn2 = 3.4e38f;
    const float b2 = by2[0];

    {   // px = sum_c wy2[c]*x[c] for first iteration
        float pxs = wy2r[0]*xcur[0] + wy2r[1]*xcur[1] + wy2r[2]*xcur[2] + wy2r[3]*xcur[3];
        pxs += __shfl_xor(pxs, 16, 64);
        pxs += __shfl_xor(pxs, 32, 64);
        if (w < 4 && l < 4) pxp[l * 4 + w] = pxs;
    }
    __syncthreads();

    const _Float16* xrow  = xact  + n4 * 80;
    const _Float16* h0row = h0act + n4 * 144;
    const _Float16* v1row = v1act + n4 * 144;
    const _Float16* v0row = v0act + n4 * 144;

    float sig0[4];
    const float T2 = TOLF * TOLF;

    for (int it = 0; it < MAX_IT; ++it) {
        // ---- loop top: prev iteration's norms (visible after end barrier) ----
        bool upd;
        {
            const float4 q0 = ((const float4*)npar)[0];
            const float4 q1 = ((const float4*)npar)[1];
            const float4 q2 = ((const float4*)npar)[2];
            const float4 q3 = ((const float4*)npar)[3];
            const float s0 = q0.x + q0.y + q0.z + q0.w;
            const float s1 = q1.x + q1.y + q1.z + q1.w;
            const float s2 = q2.x + q2.y + q2.z + q2.w;
            const float s3 = q3.x + q3.y + q3.z + q3.w;
            if (s0 < T2 && s1 < T2 && s2 < T2 && s3 < T2) break;   // uniform
            const float myn2 = (n4 == 0) ? s0 : (n4 == 1) ? s1 : (n4 == 2) ? s2 : s3;
            if (myn2 > prevn2 * 0.998f) lamE *= 0.5f;   // delayed R3 adaptation
            prevn2 = myn2;
            upd = (myn2 >= T2);                          // delayed freeze
        }

        // ---- P1: preact0 = Wy0 x + by0 -> h0, sig0 (m-tile w) ----
        f16x8 bx0 = *(const f16x8*)(xrow + quad * 8);
        f16x8 bx1 = *(const f16x8*)(xrow + 32 + quad * 8);
        {
            f32x4 acc = {0.f, 0.f, 0.f, 0.f};
            acc = MFMA(wa0[0], bx0, acc);
            acc = MFMA(wa0[1], bx1, acc);
            float sp0, sp1, sp2, sp3;
            sigsp(acc[0] + bb0.x, sig0[0], sp0);
            sigsp(acc[1] + bb0.y, sig0[1], sp1);
            sigsp(acc[2] + bb0.z, sig0[2], sp2);
            sigsp(acc[3] + bb0.w, sig0[3], sp3);
            if (n < 4)
                *(uint2*)&h0act[n4 * 144 + w * 16 + quad * 4] =
                    make_uint2(pack_h2(sp0, sp1), pack_h2(sp2, sp3));
        }
        __syncthreads();   // B1: h0 ready

        // ---- P2: preact1 -> sig1,h1 ; head partial ; ~v1 (m-tile w) ----
        f16x8 bh0 = *(const f16x8*)(h0row + quad * 8);
        f16x8 bh1 = *(const f16x8*)(h0row + 32 + quad * 8);
        f16x8 bh2 = *(const f16x8*)(h0row + 64 + quad * 8);
        f16x8 bh3 = *(const f16x8*)(h0row + 96 + quad * 8);
        float hsum = 0.0f;
        {
            f32x4 acc = {0.f, 0.f, 0.f, 0.f};
            acc = MFMA(waz[0], bh0, acc);
            acc = MFMA(waz[1], bh1, acc);
            acc = MFMA(waz[2], bh2, acc);
            acc = MFMA(waz[3], bh3, acc);
            acc = MFMA(wa1[0], bx0, acc);
            acc = MFMA(wa1[1], bx1, acc);
            float s1, h1;
            sigsp(acc[0] + bb1.x, s1, h1); hsum = fmaf(wzq.x, h1, hsum);
            const float t0 = s1 * wzq.x;
            sigsp(acc[1] + bb1.y, s1, h1); hsum = fmaf(wzq.y, h1, hsum);
            const float t1 = s1 * wzq.y;
            sigsp(acc[2] + bb1.z, s1, h1); hsum = fmaf(wzq.z, h1, hsum);
            const float t2 = s1 * wzq.z;
            sigsp(acc[3] + bb1.w, s1, h1); hsum = fmaf(wzq.w, h1, hsum);
            const float t3 = s1 * wzq.w;
            if (n < 4)
                *(uint2*)&v1act[n4 * 144 + w * 16 + quad * 4] =
                    make_uint2(pack_h2(t0, t1), pack_h2(t2, t3));
        }
        hsum += __shfl_xor(hsum, 16, 64);
        hsum += __shfl_xor(hsum, 32, 64);
        if (l < 4) hp[l * 8 + w] = hsum;   // hp[n4][w], 8 m-tiles
        __syncthreads();   // B2: hp AND ~v1 ready (sg2 deferred)

        // ---- P4: sg2; v0 = sig0*sg2*(Wz1+^T ~v1) (m-tile w); accg (cm) ----
        float sg2c;
        {
            const float4 h0v = ((const float4*)hp)[n4 * 2];
            const float4 h1v = ((const float4*)hp)[n4 * 2 + 1];
            const float4 pv  = ((const float4*)pxp)[n4];
            sg2c = sigm(h0v.x + h0v.y + h0v.z + h0v.w +
                        h1v.x + h1v.y + h1v.z + h1v.w +
                        pv.x + pv.y + pv.z + pv.w + b2);
        }
        f16x8 bv10 = *(const f16x8*)(v1row + quad * 8);
        f16x8 bv11 = *(const f16x8*)(v1row + 32 + quad * 8);
        f16x8 bv12 = *(const f16x8*)(v1row + 64 + quad * 8);
        f16x8 bv13 = *(const f16x8*)(v1row + 96 + quad * 8);
        {
            f32x4 acc = {0.f, 0.f, 0.f, 0.f};
            acc = MFMA(wzt[0], bv10, acc);
            acc = MFMA(wzt[1], bv11, acc);
            acc = MFMA(wzt[2], bv12, acc);
            acc = MFMA(wzt[3], bv13, acc);
            const float a0 = sig0[0] * sg2c * acc[0];
            const float a1 = sig0[1] * sg2c * acc[1];
            const float a2 = sig0[2] * sg2c * acc[2];
            const float a3 = sig0[3] * sg2c * acc[3];
            if (n < 4)
                *(uint2*)&v0act[n4 * 144 + w * 16 + quad * 4] =
                    make_uint2(pack_h2(a0, a1), pack_h2(a2, a3));
        }
        f32x4 accg = {0.f, 0.f, 0.f, 0.f};   // Wy1^T ~v1 (col m-tile cm)
        accg = MFMA(w1t[0], bv10, accg);
        accg = MFMA(w1t[1], bv11, accg);
        accg = MFMA(w1t[2], bv12, accg);
        accg = MFMA(w1t[3], bv13, accg);
        __syncthreads();   // B3: v0 ready

        // ---- P6: g ; fused x-update (step needs no global info) ----
        f16x8 bv00 = *(const f16x8*)(v0row + quad * 8);
        f16x8 bv01 = *(const f16x8*)(v0row + 32 + quad * 8);
        f16x8 bv02 = *(const f16x8*)(v0row + 64 + quad * 8);
        f16x8 bv03 = *(const f16x8*)(v0row + 96 + quad * 8);
        f32x4 acc0 = {0.f, 0.f, 0.f, 0.f};
        acc0 = MFMA(w0t[0], bv00, acc0);
        acc0 = MFMA(w0t[1], bv01, acc0);
        acc0 = MFMA(w0t[2], bv02, acc0);
        acc0 = MFMA(w0t[3], bv03, acc0);
        const float step = fmaxf(lamE, 1.0f / (float)(it + 2));
        float r2 = 0.0f;
        #pragma unroll
        for (int r = 0; r < 4; ++r) {
            const float g = xcur[r] + sg2c * wy2r[r] + sg2c * accg[r] + acc0[r];
            const float resid = zr[r] - g;
            r2 = fmaf(resid, resid, r2);
            if (upd) xcur[r] = fmaf(step, resid, xcur[r]);
        }
        r2 += __shfl_xor(r2, 16, 64);
        r2 += __shfl_xor(r2, 32, 64);
        if (w < 4 && l < 4) npar[l * 4 + w] = r2;   // npar[n4][cm] (read next top)
        {   // px partial for next iter
            float pxs = wy2r[0]*xcur[0] + wy2r[1]*xcur[1] + wy2r[2]*xcur[2] + wy2r[3]*xcur[3];
            pxs += __shfl_xor(pxs, 16, 64);
            pxs += __shfl_xor(pxs, 32, 64);
            if (w < 4 && l < 4) pxp[l * 4 + w] = pxs;
        }
        if (w < 4 && n < 4)
            *(uint2*)&xact[n4 * 80 + cm * 16 + quad * 4] =
                make_uint2(pack_h2(xcur[0], xcur[1]), pack_h2(xcur[2], xcur[3]));
        __syncthreads();   // B4: x/pxp/npar ready for next iteration
    }

    if (w < 4 && n < 4) {
        float4 o;
        o.x = xcur[0] + zr[0]; o.y = xcur[1] + zr[1];
        o.z = xcur[2] + zr[2]; o.w = xcur[3] + zr[3];
        ((float4*)out)[(blk4 + n4) * 16 + cm * 4 + quad] = o;   // + CONVEX*z
    }
}

extern "C" void kernel_launch(void* const* d_in, const int* in_sizes, int n_in,
                              void* d_out, int out_size, void* d_ws, size_t ws_size,
                              hipStream_t stream) {
    const float* xin = (const float*)d_in[0];
    const float* Wy0 = (const float*)d_in[1];
    const float* by0 = (const float*)d_in[2];
    const float* Wy1 = (const float*)d_in[3];
    const float* by1 = (const float*)d_in[4];
    const float* Wz1 = (const float*)d_in[5];
    const float* Wy2 = (const float*)d_in[6];
    const float* by2 = (const float*)d_in[7];
    const float* Wz2 = (const float*)d_in[8];
    float* out = (float*)d_out;

    blnn_kernel<<<dim3(NB / 4), dim3(512), 0, stream>>>(
        xin, Wy0, by0, Wy1, by1, Wz1, Wy2, by2, Wz2, out);
}

// Round 9
// 82.227 us; speedup vs baseline: 1.2711x; 1.0221x over previous
//
#include <hip/hip_runtime.h>
#include <math.h>

#define NB 1024   // batch
#define NC 64     // input dim
#define NH 128    // hidden dim
#define MAX_IT 100   // R25 probe: 200 -> 100. Model: worst block runs k*~190
                     // because permanent lamE-halvings (0.998 test fires on
                     // fp16 noise) drop the step to the 1/(it+2) floor =>
                     // HARMONIC tail, r ~ 1/k, k*~200 to reach 6e-3. Capping
                     // at 100 bounds the tail; capped error <= ||r_100||
                     // (1-strong mono), budget: absmax 0.031 now vs 0.169
                     // threshold. Duration responds linearly to the cap when
                     // cap < k* => this round MEASURES k* via dur.
#define TOLF 6e-3f   // ||r|| < TOL certifies ||x-x*|| < TOL (1-strong mono).

typedef _Float16 f16x8 __attribute__((ext_vector_type(8)));
typedef float    f32x4 __attribute__((ext_vector_type(4)));
typedef _Float16 h2    __attribute__((ext_vector_type(2)));

#define MFMA(a, b, c) __builtin_amdgcn_mfma_f32_16x16x32_f16((a), (b), (c), 0, 0, 0)

__device__ __forceinline__ unsigned pack_h2(float a, float b) {
    union { h2 h; unsigned u; } cv;
    cv.h.x = (_Float16)a; cv.h.y = (_Float16)b; return cv.u;
}
__device__ __forceinline__ float rcp_fast(float x) {
#if __has_builtin(__builtin_amdgcn_rcpf)
    return __builtin_amdgcn_rcpf(x);
#else
    return 1.0f / x;
#endif
}
// sigmoid + softplus sharing one exp
__device__ __forceinline__ void sigsp(float a, float& sig, float& sp) {
    const float e = __expf(-fabsf(a));
    const float r = rcp_fast(1.0f + e);
    sig = (a >= 0.0f) ? r : e * r;
    sp  = fmaxf(a, 0.0f) + __logf(1.0f + e);
}
__device__ __forceinline__ float sigm(float a) {
    const float e = __expf(-fabsf(a));
    const float r = rcp_fast(1.0f + e);
    return (a >= 0.0f) ? r : e * r;
}
__device__ __forceinline__ float clp(float x) { return fmaxf(x, 0.0f); }

// fragment loaders: 8 fp32 -> f16x8, same element order as the old LDS staging
__device__ __forceinline__ f16x8 ld8(const float* p) {
    const float4 a = ((const float4*)p)[0];
    const float4 b = ((const float4*)p)[1];
    f16x8 r;
    r[0]=(_Float16)a.x; r[1]=(_Float16)a.y; r[2]=(_Float16)a.z; r[3]=(_Float16)a.w;
    r[4]=(_Float16)b.x; r[5]=(_Float16)b.y; r[6]=(_Float16)b.z; r[7]=(_Float16)b.w;
    return r;
}
__device__ __forceinline__ f16x8 ld8_clip(const float* p) {
    const float4 a = ((const float4*)p)[0];
    const float4 b = ((const float4*)p)[1];
    f16x8 r;
    r[0]=(_Float16)clp(a.x); r[1]=(_Float16)clp(a.y); r[2]=(_Float16)clp(a.z); r[3]=(_Float16)clp(a.w);
    r[4]=(_Float16)clp(b.x); r[5]=(_Float16)clp(b.y); r[6]=(_Float16)clp(b.z); r[7]=(_Float16)clp(b.w);
    return r;
}
__device__ __forceinline__ f16x8 ld8_str(const float* p, int stride) {
    f16x8 r;
    #pragma unroll
    for (int j = 0; j < 8; ++j) r[j] = (_Float16)p[j * stride];
    return r;
}
__device__ __forceinline__ f16x8 ld8_str_clip(const float* p, int stride) {
    f16x8 r;
    #pragma unroll
    for (int j = 0; j < 8; ++j) r[j] = (_Float16)clp(p[j * stride]);
    return r;
}

// R25 = R21 EXACTLY (5 barriers, adaptive Richardson, weights-in-regs,
// 83.3 us measured) with MAX_IT 200 -> 100. Single-variable probe of k*.
// Evidence ledger: R18 operand-fetch removal neutral; R24 barrier 5->4 +
// solver-region removal neutral; R22 fixed-step +20us (adaptivity is load-
// bearing); R23 2-blk/CU spilled (VGPR=128 cap, MfmaUtil 3%). => t_iter is
// latency-bound and insensitive to structure; duration = k* x t_iter with
// k* ~ 170-200 (harmonic solver tail). This round measures k* via the cap.
__launch_bounds__(512, 1)
__global__ void blnn_kernel(const float* __restrict__ xin,
                            const float* __restrict__ Wy0,
                            const float* __restrict__ by0,
                            const float* __restrict__ Wy1,
                            const float* __restrict__ by1,
                            const float* __restrict__ Wz1,
                            const float* __restrict__ Wy2,
                            const float* __restrict__ by2,
                            const float* __restrict__ Wz2,
                            float* __restrict__ out)
{
    __shared__ __align__(16) _Float16 xact [4 * 80];   // x  per sample (pad 64->80)
    __shared__ __align__(16) _Float16 h0act[4 * 144];  // h0 per sample (pad 128->144)
    __shared__ __align__(16) _Float16 v1act[4 * 144];  // ~v1 (no sg2)
    __shared__ __align__(16) _Float16 v0act[4 * 144];
    __shared__ __align__(16) float hp[32];    // head partials [n4][w0..7]
    __shared__ __align__(16) float pxp[16];   // wy2.x partials [n4][cm]
    __shared__ __align__(16) float npar[16];  // norm^2 partials [n4][cm]

    const int tid  = threadIdx.x;
    const int w    = tid >> 6;        // 0..7
    const int cm   = w & 3;           // col-phase m-tile (pairs duplicate)
    const int l    = tid & 63;
    const int n    = l & 15;          // MFMA col
    const int n4   = n & 3;           // real sample
    const int quad = l >> 4;
    const int blk4 = blockIdx.x * 4;

    // ---- weights into REGISTERS (one-time; same frag order as R9 staging) ----
    const int rA = w * 16 + n;        // forward m-tile row, 0..127
    const int rT = cm * 16 + n;       // transposed row (c index), 0..63
    const int kq = quad * 8;

    f16x8 wa0[2], wa1[2];
    #pragma unroll
    for (int ks = 0; ks < 2; ++ks) {
        wa0[ks] = ld8(Wy0 + rA * 64 + ks * 32 + kq);
        wa1[ks] = ld8(Wy1 + rA * 64 + ks * 32 + kq);
    }
    f16x8 waz[4], wzt[4], w1t[4], w0t[4];
    #pragma unroll
    for (int ks = 0; ks < 4; ++ks) {
        waz[ks] = ld8_clip(Wz1 + rA * 128 + ks * 32 + kq);                 // Wz1+ row-major
        wzt[ks] = ld8_str_clip(Wz1 + (ks * 32 + kq) * 128 + rA, 128);      // Wz1+^T
        w1t[ks] = ld8_str(Wy1 + (ks * 32 + kq) * 64 + rT, 64);             // Wy1^T
        w0t[ks] = ld8_str(Wy0 + (ks * 32 + kq) * 64 + rT, 64);             // Wy0^T
    }
    const float4 bb0 = *(const float4*)(by0 + w * 16 + quad * 4);
    const float4 bb1 = *(const float4*)(by1 + w * 16 + quad * 4);
    float4 wzq;
    {
        const float4 t = *(const float4*)(Wz2 + w * 16 + quad * 4);
        wzq.x = clp(t.x); wzq.y = clp(t.y); wzq.z = clp(t.z); wzq.w = clp(t.w);
    }

    if (tid < 256) {   // x0 = z into act layout
        const int nn = tid >> 6, cc = tid & 63;
        xact[nn * 80 + cc] = (_Float16)xin[(blk4 + nn) * 64 + cc];
    }

    // ---- col-role state: rows c = cm*16 + quad*4 + r, sample n4 ----
    const float4 z4  = ((const float4*)xin)[(blk4 + n4) * 16 + cm * 4 + quad];
    const float4 wy4 = ((const float4*)Wy2)[cm * 4 + quad];
    float zr[4]   = {z4.x, z4.y, z4.z, z4.w};
    float wy2r[4] = {wy4.x, wy4.y, wy4.z, wy4.w};
    float xcur[4] = {zr[0], zr[1], zr[2], zr[3]};
    float lamE = 1.0f, prevn2 = 3.4e38f;
    const float b2 = by2[0];

    {   // px = sum_c wy2[c]*x[c] for first iteration
        float pxs = wy2r[0]*xcur[0] + wy2r[1]*xcur[1] + wy2r[2]*xcur[2] + wy2r[3]*xcur[3];
        pxs += __shfl_xor(pxs, 16, 64);
        pxs += __shfl_xor(pxs, 32, 64);
        if (w < 4 && l < 4) pxp[l * 4 + w] = pxs;
    }
    __syncthreads();

    const _Float16* xrow  = xact  + n4 * 80;
    const _Float16* h0row = h0act + n4 * 144;
    const _Float16* v1row = v1act + n4 * 144;
    const _Float16* v0row = v0act + n4 * 144;

    float sig0[4];

    for (int it = 0; it < MAX_IT; ++it) {
        // ---- P1: preact0 = Wy0 x + by0 -> h0, sig0 (m-tile w) ----
        f16x8 bx0 = *(const f16x8*)(xrow + quad * 8);
        f16x8 bx1 = *(const f16x8*)(xrow + 32 + quad * 8);
        {
            f32x4 acc = {0.f, 0.f, 0.f, 0.f};
            acc = MFMA(wa0[0], bx0, acc);
            acc = MFMA(wa0[1], bx1, acc);
            float sp0, sp1, sp2, sp3;
            sigsp(acc[0] + bb0.x, sig0[0], sp0);
            sigsp(acc[1] + bb0.y, sig0[1], sp1);
            sigsp(acc[2] + bb0.z, sig0[2], sp2);
            sigsp(acc[3] + bb0.w, sig0[3], sp3);
            if (n < 4)
                *(uint2*)&h0act[n4 * 144 + w * 16 + quad * 4] =
                    make_uint2(pack_h2(sp0, sp1), pack_h2(sp2, sp3));
        }
        __syncthreads();   // B1: h0 ready

        // ---- P2: preact1 -> sig1,h1 ; head partial ; ~v1 (m-tile w) ----
        f16x8 bh0 = *(const f16x8*)(h0row + quad * 8);
        f16x8 bh1 = *(const f16x8*)(h0row + 32 + quad * 8);
        f16x8 bh2 = *(const f16x8*)(h0row + 64 + quad * 8);
        f16x8 bh3 = *(const f16x8*)(h0row + 96 + quad * 8);
        float hsum = 0.0f;
        {
            f32x4 acc = {0.f, 0.f, 0.f, 0.f};
            acc = MFMA(waz[0], bh0, acc);
            acc = MFMA(waz[1], bh1, acc);
            acc = MFMA(waz[2], bh2, acc);
            acc = MFMA(waz[3], bh3, acc);
            acc = MFMA(wa1[0], bx0, acc);
            acc = MFMA(wa1[1], bx1, acc);
            float s1, h1;
            sigsp(acc[0] + bb1.x, s1, h1); hsum = fmaf(wzq.x, h1, hsum);
            const float t0 = s1 * wzq.x;
            sigsp(acc[1] + bb1.y, s1, h1); hsum = fmaf(wzq.y, h1, hsum);
            const float t1 = s1 * wzq.y;
            sigsp(acc[2] + bb1.z, s1, h1); hsum = fmaf(wzq.z, h1, hsum);
            const float t2 = s1 * wzq.z;
            sigsp(acc[3] + bb1.w, s1, h1); hsum = fmaf(wzq.w, h1, hsum);
            const float t3 = s1 * wzq.w;
            if (n < 4)
                *(uint2*)&v1act[n4 * 144 + w * 16 + quad * 4] =
                    make_uint2(pack_h2(t0, t1), pack_h2(t2, t3));
        }
        hsum += __shfl_xor(hsum, 16, 64);
        hsum += __shfl_xor(hsum, 32, 64);
        if (l < 4) hp[l * 8 + w] = hsum;   // hp[n4][w], 8 m-tiles
        __syncthreads();   // B2: hp AND ~v1 ready (sg2 deferred)

        // ---- P4: sg2; v0 = sig0*sg2*(Wz1+^T ~v1) (m-tile w); accg (cm) ----
        float sg2c;
        {
            const float4 h0v = ((const float4*)hp)[n4 * 2];
            const float4 h1v = ((const float4*)hp)[n4 * 2 + 1];
            const float4 pv  = ((const float4*)pxp)[n4];
            sg2c = sigm(h0v.x + h0v.y + h0v.z + h0v.w +
                        h1v.x + h1v.y + h1v.z + h1v.w +
                        pv.x + pv.y + pv.z + pv.w + b2);
        }
        f16x8 bv10 = *(const f16x8*)(v1row + quad * 8);
        f16x8 bv11 = *(const f16x8*)(v1row + 32 + quad * 8);
        f16x8 bv12 = *(const f16x8*)(v1row + 64 + quad * 8);
        f16x8 bv13 = *(const f16x8*)(v1row + 96 + quad * 8);
        {
            f32x4 acc = {0.f, 0.f, 0.f, 0.f};
            acc = MFMA(wzt[0], bv10, acc);
            acc = MFMA(wzt[1], bv11, acc);
            acc = MFMA(wzt[2], bv12, acc);
            acc = MFMA(wzt[3], bv13, acc);
            const float a0 = sig0[0] * sg2c * acc[0];
            const float a1 = sig0[1] * sg2c * acc[1];
            const float a2 = sig0[2] * sg2c * acc[2];
            const float a3 = sig0[3] * sg2c * acc[3];
            if (n < 4)
                *(uint2*)&v0act[n4 * 144 + w * 16 + quad * 4] =
                    make_uint2(pack_h2(a0, a1), pack_h2(a2, a3));
        }
        f32x4 accg = {0.f, 0.f, 0.f, 0.f};   // Wy1^T ~v1 (col m-tile cm)
        accg = MFMA(w1t[0], bv10, accg);
        accg = MFMA(w1t[1], bv11, accg);
        accg = MFMA(w1t[2], bv12, accg);
        accg = MFMA(w1t[3], bv13, accg);
        __syncthreads();   // B3: v0 ready

        // ---- P6: g = x + sg2*wy2 + sg2*accg + Wy0^T v0 ; residual norm ----
        f16x8 bv00 = *(const f16x8*)(v0row + quad * 8);
        f16x8 bv01 = *(const f16x8*)(v0row + 32 + quad * 8);
        f16x8 bv02 = *(const f16x8*)(v0row + 64 + quad * 8);
        f16x8 bv03 = *(const f16x8*)(v0row + 96 + quad * 8);
        f32x4 acc0 = {0.f, 0.f, 0.f, 0.f};
        acc0 = MFMA(w0t[0], bv00, acc0);
        acc0 = MFMA(w0t[1], bv01, acc0);
        acc0 = MFMA(w0t[2], bv02, acc0);
        acc0 = MFMA(w0t[3], bv03, acc0);
        float resid[4];
        float r2 = 0.0f;
        #pragma unroll
        for (int r = 0; r < 4; ++r) {
            const float g = xcur[r] + sg2c * wy2r[r] + sg2c * accg[r] + acc0[r];
            resid[r] = zr[r] - g;
            r2 = fmaf(resid[r], resid[r], r2);
        }
        r2 += __shfl_xor(r2, 16, 64);
        r2 += __shfl_xor(r2, 32, 64);
        if (w < 4 && l < 4) npar[l * 4 + w] = r2;   // npar[n4][cm]
        __syncthreads();   // B4: norm partials ready

        const float4 q0 = ((const float4*)npar)[0];
        const float4 q1 = ((const float4*)npar)[1];
        const float4 q2 = ((const float4*)npar)[2];
        const float4 q3 = ((const float4*)npar)[3];
        const float s0 = q0.x + q0.y + q0.z + q0.w;
        const float s1 = q1.x + q1.y + q1.z + q1.w;
        const float s2 = q2.x + q2.y + q2.z + q2.w;
        const float s3 = q3.x + q3.y + q3.z + q3.w;
        const float T2 = TOLF * TOLF;
        if (s0 < T2 && s1 < T2 && s2 < T2 && s3 < T2) break;   // uniform

        const float myn2 = (n4 == 0) ? s0 : (n4 == 1) ? s1 : (n4 == 2) ? s2 : s3;
        if (myn2 >= T2) {                    // adaptive Richardson (R3 solver)
            if (myn2 > prevn2 * 0.998f) lamE *= 0.5f;
            const float step = fmaxf(lamE, 1.0f / (float)(it + 2));
            #pragma unroll
            for (int r = 0; r < 4; ++r) xcur[r] = fmaf(step, resid[r], xcur[r]);
            prevn2 = myn2;
        }
        {   // px partial for next iter + x writeback
            float pxs = wy2r[0]*xcur[0] + wy2r[1]*xcur[1] + wy2r[2]*xcur[2] + wy2r[3]*xcur[3];
            pxs += __shfl_xor(pxs, 16, 64);
            pxs += __shfl_xor(pxs, 32, 64);
            if (w < 4 && l < 4) pxp[l * 4 + w] = pxs;
        }
        if (w < 4 && n < 4)
            *(uint2*)&xact[n4 * 80 + cm * 16 + quad * 4] =
                make_uint2(pack_h2(xcur[0], xcur[1]), pack_h2(xcur[2], xcur[3]));
        __syncthreads();   // B5: x ready
    }

    if (w < 4 && n < 4) {
        float4 o;
        o.x = xcur[0] + zr[0]; o.y = xcur[1] + zr[1];
        o.z = xcur[2] + zr[2]; o.w = xcur[3] + zr[3];
        ((float4*)out)[(blk4 + n4) * 16 + cm * 4 + quad] = o;   // + CONVEX*z
    }
}

extern "C" void kernel_launch(void* const* d_in, const int* in_sizes, int n_in,
                              void* d_out, int out_size, void* d_ws, size_t ws_size,
                              hipStream_t stream) {
    const float* xin = (const float*)d_in[0];
    const float* Wy0 = (const float*)d_in[1];
    const float* by0 = (const float*)d_in[2];
    const float* Wy1 = (const float*)d_in[3];
    const float* by1 = (const float*)d_in[4];
    const float* Wz1 = (const float*)d_in[5];
    const float* Wy2 = (const float*)d_in[6];
    const float* by2 = (const float*)d_in[7];
    const float* Wz2 = (const float*)d_in[8];
    float* out = (float*)d_out;

    blnn_kernel<<<dim3(NB / 4), dim3(512), 0, stream>>>(
        xin, Wy0, by0, Wy1, by1, Wz1, Wy2, by2, Wz2, out);
}